// Round 4
// baseline (1715.972 us; speedup 1.0000x reference)
//
#include <hip/hip_runtime.h>
#include <stdint.h>

#define NB 8
#define NN 4096
#define NP 1024
#define NSAMP 32
#define CIN 64
#define C0IN 67
#define C3 128

__device__ __forceinline__ float lo2f(unsigned int u) { return __uint_as_float(u << 16); }
__device__ __forceinline__ float hi2f(unsigned int u) { return __uint_as_float(u & 0xffff0000u); }
__device__ __forceinline__ unsigned short f2b(float f) {
  unsigned int u = __float_as_uint(f);
  unsigned int r = u + 0x7fffu + ((u >> 16) & 1u);
  return (unsigned short)(r >> 16);
}

// ---- Kernel 1: farthest point sampling --------------------------------------
// 512 threads, 8 points/thread, contiguous mapping (thread t holds pts t*8..t*8+7)
// so lane order == index order; ties resolve to lowest index like np.argmax.
// One barrier per iteration, no global ops inside the loop.
__global__ __launch_bounds__(512) void fps_kernel(
    const float* __restrict__ xyz, unsigned short* __restrict__ fps_g,
    float* __restrict__ out_xyz) {
#pragma clang fp contract(off)
  __shared__ float sx[NN], sy[NN], sz[NN];
  __shared__ float sval[2][8], sxc[2][8], syc[2][8], szc[2][8];
  __shared__ int sidx[2][8];
  __shared__ unsigned short scidx[NP];
  const int b = blockIdx.x;
  const int tid = threadIdx.x;
  const int lane = tid & 63;
  const int w8 = tid >> 6;
  const float* xb = xyz + (size_t)b * NN * 3;
  for (int i = tid; i < NN; i += 512) {
    sx[i] = xb[3 * i + 0];
    sy[i] = xb[3 * i + 1];
    sz[i] = xb[3 * i + 2];
  }
  if (tid == 0) scidx[0] = 0;
  __syncthreads();
  float px[8], py[8], pz[8], dist[8];
#pragma unroll
  for (int j = 0; j < 8; ++j) {
    int i = tid * 8 + j;
    px[j] = sx[i]; py[j] = sy[i]; pz[j] = sz[i];
    dist[j] = 1e10f;
  }
  float qx = sx[0], qy = sy[0], qz = sz[0];
  for (int k = 1; k < NP; ++k) {
    float best = -1.0f, bx = 0.f, by = 0.f, bz = 0.f;
    int bj = 0;
#pragma unroll
    for (int j = 0; j < 8; ++j) {
      float dx = px[j] - qx;
      float dy = py[j] - qy;
      float dz = pz[j] - qz;
      float xx = dx * dx, yy = dy * dy, zz = dz * dz;
      float s = xx + yy;
      float d = s + zz;            // ((dx^2+dy^2)+dz^2), np order, no fma
      float nd = fminf(dist[j], d);
      dist[j] = nd;
      bool g = nd > best;          // strict > keeps smallest j on ties
      best = g ? nd : best;
      bj = g ? j : bj;
      bx = g ? px[j] : bx; by = g ? py[j] : by; bz = g ? pz[j] : bz;
    }
    float mx = best;
#pragma unroll
    for (int off = 32; off > 0; off >>= 1) mx = fmaxf(mx, __shfl_xor(mx, off, 64));
    unsigned long long mball = __ballot(best == mx);
    int wl = __ffsll((long long)mball) - 1;  // lowest lane == lowest index
    const int kb = k & 1;
    if (lane == wl) {
      sval[kb][w8] = mx; sidx[kb][w8] = tid * 8 + bj;
      sxc[kb][w8] = bx; syc[kb][w8] = by; szc[kb][w8] = bz;
    }
    __syncthreads();
    float bb = sval[kb][0];
    float nqx = sxc[kb][0], nqy = syc[kb][0], nqz = szc[kb][0];
    int wsel = 0;
#pragma unroll
    for (int w = 1; w < 8; ++w) {
      float v = sval[kb][w];
      bool g = v > bb;             // strict >: ties -> smallest wave = smallest idx
      bb = g ? v : bb;
      nqx = g ? sxc[kb][w] : nqx; nqy = g ? syc[kb][w] : nqy; nqz = g ? szc[kb][w] : nqz;
      wsel = g ? w : wsel;
    }
    qx = nqx; qy = nqy; qz = nqz;
    if (tid == 0) scidx[k] = (unsigned short)sidx[kb][wsel];
  }
  __syncthreads();
  for (int i = tid; i < NP; i += 512) {
    int id = scidx[i];
    out_xyz[((size_t)b * NP + i) * 3 + 0] = sx[id];
    out_xyz[((size_t)b * NP + i) * 3 + 1] = sy[id];
    out_xyz[((size_t)b * NP + i) * 3 + 2] = sz[id];
    fps_g[b * NP + i] = (unsigned short)id;
  }
}

// ---- Kernel 2: ball query (one wave per center) ----------------------------
__global__ __launch_bounds__(256) void ballq_kernel(
    const float* __restrict__ xyz, const unsigned short* __restrict__ fps_idx,
    unsigned short* __restrict__ gidx) {
#pragma clang fp contract(off)
  const int tid = threadIdx.x;
  const int gid = blockIdx.x * 4 + (tid >> 6);
  const int lane = tid & 63;
  const int b = gid >> 10;
  const int s = gid & 1023;
  const float* xb = xyz + (size_t)b * NN * 3;
  const int ci = (int)fps_idx[b * NP + s] & (NN - 1);
  const float cx = xb[ci * 3 + 0];
  const float cy = xb[ci * 3 + 1];
  const float cz = xb[ci * 3 + 2];
  const float nn = (cx * cx + cy * cy) + cz * cz;
  const float r2 = 0.04f;
  unsigned short* gout = gidx + (size_t)(b * NP + s) * NSAMP;
  int total = 0;
  int first = -1;
  for (int c = 0; c < NN / 64 && total < NSAMP; ++c) {
    int i = (c << 6) + lane;
    float x = xb[i * 3 + 0];
    float y = xb[i * 3 + 1];
    float z = xb[i * 3 + 2];
    float pp = (x * x + y * y) + z * z;
    float dt = (x * cx + y * cy) + z * cz;
    float sq = (nn + pp) - 2.0f * dt;  // exact ref formula; self-dist == 0
    bool inb = !(sq > r2);
    unsigned long long m = __ballot(inb);
    if (first < 0 && m) first = (c << 6) + (__ffsll((unsigned long long)m) - 1);
    int before = __popcll(m & ((1ull << lane) - 1ull));
    int slot = total + before;
    if (inb && slot < NSAMP) gout[slot] = (unsigned short)i;
    total += (int)__popcll(m);
  }
  int cnt = total < NSAMP ? total : NSAMP;
  unsigned short fill = (unsigned short)(first < 0 ? 0 : first);
  if (lane >= cnt && lane < NSAMP) gout[lane] = fill;
}

// ---- Kernel 3: gather + MLP(67->64->64->128) + max -------------------------
// Row-per-thread: 256 threads = 8 centers x 32 rows. Accumulators in regs,
// hidden h stored bf16-packed in thread-private LDS rows. Weights staged per
// layer (W2 in two 64-col halves), amortized over 8 centers. All weight reads
// are same-address broadcasts (conflict-free).
__global__ __launch_bounds__(256) void mlp_kernel(
    const float* __restrict__ xyz, const float* __restrict__ points,
    const unsigned short* __restrict__ fps_idx, const unsigned short* __restrict__ gidx,
    const float* __restrict__ W0, const float* __restrict__ b0,
    const float* __restrict__ g0, const float* __restrict__ be0,
    const float* __restrict__ W1, const float* __restrict__ b1,
    const float* __restrict__ g1, const float* __restrict__ be1,
    const float* __restrict__ W2, const float* __restrict__ b2,
    const float* __restrict__ g2, const float* __restrict__ be2,
    float* __restrict__ out_feat) {
  __shared__ __align__(16) float wbuf[4352];        // 17 KB: max layer stage (W0)
  __shared__ __align__(16) unsigned int hbuf[256 * 33];  // 33 KB: bf16 h rows, stride 33
  __shared__ float prm[768];
  const int tid = threadIdx.x;
  const int j = tid & 31;            // row (sample) 0..31
  const int cb = tid >> 5;           // center-in-block 0..7
  const int sg = blockIdx.x * 8 + cb;
  const int b = sg >> 10;
  const int s = sg & 1023;
  const float bnsc = 1.0f / sqrtf(1.001f);
  if (tid < 64) {
    prm[tid] = b0[tid];       prm[64 + tid] = g0[tid] * bnsc;  prm[128 + tid] = be0[tid];
    prm[192 + tid] = b1[tid]; prm[256 + tid] = g1[tid] * bnsc; prm[320 + tid] = be1[tid];
  }
  if (tid < 128) {
    prm[384 + tid] = b2[tid]; prm[512 + tid] = g2[tid] * bnsc; prm[640 + tid] = be2[tid];
  }
  for (int i = tid; i < C0IN * 64; i += 256) wbuf[i] = W0[i];
  const int idx = (int)gidx[(size_t)(b * NP + s) * NSAMP + j] & (NN - 1);
  const int ci = (int)fps_idx[b * NP + s] & (NN - 1);
  const float* xbp = xyz + (size_t)b * NN * 3;
  const float x0 = xbp[idx * 3 + 0] - xbp[ci * 3 + 0];
  const float x1 = xbp[idx * 3 + 1] - xbp[ci * 3 + 1];
  const float x2 = xbp[idx * 3 + 2] - xbp[ci * 3 + 2];
  const float4* prow = (const float4*)(points + ((size_t)b * NN + idx) * CIN);
  float acc[64];
  auto fma64 = [&](float xv, const float* wrow) {
#pragma unroll
    for (int c4 = 0; c4 < 16; ++c4) {
      float4 w = *(const float4*)(wrow + c4 * 4);
      acc[c4 * 4 + 0] = fmaf(xv, w.x, acc[c4 * 4 + 0]);
      acc[c4 * 4 + 1] = fmaf(xv, w.y, acc[c4 * 4 + 1]);
      acc[c4 * 4 + 2] = fmaf(xv, w.z, acc[c4 * 4 + 2]);
      acc[c4 * 4 + 3] = fmaf(xv, w.w, acc[c4 * 4 + 3]);
    }
  };
  __syncthreads();
  // ---- layer 0: 67 -> 64
#pragma unroll
  for (int c = 0; c < 64; ++c) acc[c] = 0.f;
  fma64(x0, &wbuf[0]);
  fma64(x1, &wbuf[64]);
  fma64(x2, &wbuf[128]);
#pragma unroll 1
  for (int kk = 0; kk < 16; ++kk) {
    float4 v = prow[kk];
    const float* wr = &wbuf[(3 + kk * 4) * 64];
    fma64(v.x, wr);
    fma64(v.y, wr + 64);
    fma64(v.z, wr + 128);
    fma64(v.w, wr + 192);
  }
  unsigned int* hrow = &hbuf[tid * 33];
#pragma unroll
  for (int c2 = 0; c2 < 32; ++c2) {
    float za = acc[2 * c2] + prm[2 * c2];
    za = za > 0.f ? za : 0.f;
    za = za * prm[64 + 2 * c2] + prm[128 + 2 * c2];
    float zb = acc[2 * c2 + 1] + prm[2 * c2 + 1];
    zb = zb > 0.f ? zb : 0.f;
    zb = zb * prm[64 + 2 * c2 + 1] + prm[128 + 2 * c2 + 1];
    hrow[c2] = (unsigned int)f2b(za) | ((unsigned int)f2b(zb) << 16);
  }
  __syncthreads();
  // ---- stage W1, layer 1: 64 -> 64
  for (int i = tid; i < 64 * 64; i += 256) wbuf[i] = W1[i];
  __syncthreads();
#pragma unroll
  for (int c = 0; c < 64; ++c) acc[c] = 0.f;
#pragma unroll 1
  for (int k2 = 0; k2 < 32; ++k2) {
    unsigned int hp = hrow[k2];
    const float* wr = &wbuf[k2 * 128];
    fma64(lo2f(hp), wr);
    fma64(hi2f(hp), wr + 64);
  }
  __syncthreads();   // done reading W1 and h0
#pragma unroll
  for (int c2 = 0; c2 < 32; ++c2) {
    float za = acc[2 * c2] + prm[192 + 2 * c2];
    za = za > 0.f ? za : 0.f;
    za = za * prm[256 + 2 * c2] + prm[320 + 2 * c2];
    float zb = acc[2 * c2 + 1] + prm[192 + 2 * c2 + 1];
    zb = zb > 0.f ? zb : 0.f;
    zb = zb * prm[256 + 2 * c2 + 1] + prm[320 + 2 * c2 + 1];
    hrow[c2] = (unsigned int)f2b(za) | ((unsigned int)f2b(zb) << 16);
  }
  // ---- layer 2: 64 -> 128 in two 64-col halves
  float* outp = out_feat + (size_t)(b * NP + s) * C3;
#pragma unroll 1
  for (int half = 0; half < 2; ++half) {
    __syncthreads();   // h ready (half 0) / prev half done reading wbuf (half 1)
    for (int i = tid; i < 4096; i += 256)
      wbuf[i] = W2[(i >> 6) * C3 + half * 64 + (i & 63)];
    __syncthreads();
#pragma unroll
    for (int c = 0; c < 64; ++c) acc[c] = 0.f;
#pragma unroll 1
    for (int k2 = 0; k2 < 32; ++k2) {
      unsigned int hp = hrow[k2];
      const float* wr = &wbuf[k2 * 128];
      fma64(lo2f(hp), wr);
      fma64(hi2f(hp), wr + 64);
    }
#pragma unroll
    for (int c = 0; c < 64; ++c) {
      int cg = half * 64 + c;
      float z = acc[c] + prm[384 + cg];
      z = z > 0.f ? z : 0.f;
      float v = z * prm[512 + cg] + prm[640 + cg];
      v = fmaxf(v, __shfl_xor(v, 16, 32));
      v = fmaxf(v, __shfl_xor(v, 8, 32));
      v = fmaxf(v, __shfl_xor(v, 4, 32));
      v = fmaxf(v, __shfl_xor(v, 2, 32));
      v = fmaxf(v, __shfl_xor(v, 1, 32));
      if (j == 0) outp[cg] = v;
    }
  }
}

extern "C" void kernel_launch(void* const* d_in, const int* in_sizes, int n_in,
                              void* d_out, int out_size, void* d_ws, size_t ws_size,
                              hipStream_t stream) {
  const float* xyz = (const float*)d_in[0];
  const float* points = (const float*)d_in[1];
  const float* W0 = (const float*)d_in[2];
  const float* b0 = (const float*)d_in[3];
  const float* g0 = (const float*)d_in[4];
  const float* be0 = (const float*)d_in[5];
  const float* W1 = (const float*)d_in[6];
  const float* b1 = (const float*)d_in[7];
  const float* g1 = (const float*)d_in[8];
  const float* be1 = (const float*)d_in[9];
  const float* W2 = (const float*)d_in[10];
  const float* b2 = (const float*)d_in[11];
  const float* g2 = (const float*)d_in[12];
  const float* be2 = (const float*)d_in[13];
  float* out = (float*)d_out;
  unsigned short* fps = (unsigned short*)d_ws;          // 16 KB
  unsigned short* gidx = fps + (size_t)NB * NP;         // 512 KB
  fps_kernel<<<NB, 512, 0, stream>>>(xyz, fps, out);
  ballq_kernel<<<(NB * NP) / 4, 256, 0, stream>>>(xyz, fps, gidx);
  mlp_kernel<<<(NB * NP) / 8, 256, 0, stream>>>(xyz, points, fps, gidx,
                                                W0, b0, g0, be0, W1, b1, g1, be1,
                                                W2, b2, g2, be2,
                                                out + (size_t)NB * NP * 3);
}